// Round 5
// baseline (372.426 us; speedup 1.0000x reference)
//
#include <hip/hip_runtime.h>
#include <hip/hip_bf16.h>

// ---------- types ----------
typedef short bf16x8 __attribute__((ext_vector_type(8)));
typedef unsigned short u16x8 __attribute__((ext_vector_type(8)));
typedef unsigned short us4 __attribute__((ext_vector_type(4)));
typedef float f32x4 __attribute__((ext_vector_type(4)));
using bf16 = __hip_bfloat16;

#define EMB 768
#define NHEAD 12
#define BATCH 8
#define NTOK 4096
#define BNTOK 32768

__device__ __forceinline__ float b2f(unsigned short u) {
    union { unsigned int i; float f; } x; x.i = ((unsigned int)u) << 16; return x.f;
}
__device__ __forceinline__ unsigned short f2bu(float f) {
    bf16 h = __float2bfloat16(f);
    return *reinterpret_cast<unsigned short*>(&h);
}

__device__ __forceinline__ void gload_lds16(const void* g, void* l) {
    __builtin_amdgcn_global_load_lds(
        (const __attribute__((address_space(1))) unsigned int*)g,
        (__attribute__((address_space(3))) unsigned int*)l,
        16, 0, 0);
}

// ---------- cast x (fp32 -> bf16) ----------
__global__ __launch_bounds__(256) void cast_x_kernel(const float* __restrict__ x,
                                                     bf16* __restrict__ xb, int n8) {
    int i = blockIdx.x * blockDim.x + threadIdx.x;
    if (i >= n8) return;
    const float4* xv = (const float4*)x;
    float4 a = xv[i * 2], b = xv[i * 2 + 1];
    u16x8 o;
    o[0] = f2bu(a.x); o[1] = f2bu(a.y); o[2] = f2bu(a.z); o[3] = f2bu(a.w);
    o[4] = f2bu(b.x); o[5] = f2bu(b.y); o[6] = f2bu(b.z); o[7] = f2bu(b.w);
    ((u16x8*)xb)[i] = o;
}

// ---------- weight prep ----------
__global__ __launch_bounds__(256) void prep_w_kernel(
    const float* __restrict__ Wq, const float* __restrict__ Wk,
    const float* __restrict__ Wv, const float* __restrict__ Wo,
    const float* __restrict__ bq, const float* __restrict__ bk, const float* __restrict__ bv,
    bf16* __restrict__ WqkvT, bf16* __restrict__ WoT, float* __restrict__ bqkv) {
    const int NQKV = 2304 * 768, NO = 768 * 768;
    int i = blockIdx.x * blockDim.x + threadIdx.x;
    if (i < NQKV) {
        int nrow = i / 768, k = i % 768;
        const float* W = (nrow < 768) ? Wq : (nrow < 1536 ? Wk : Wv);
        int c = nrow % 768;
        WqkvT[i] = __float2bfloat16(W[k * 768 + c]);
    } else if (i < NQKV + NO) {
        int j = i - NQKV; int nrow = j / 768, k = j % 768;
        WoT[j] = __float2bfloat16(Wo[k * 768 + nrow]);
    } else if (i < NQKV + NO + 2304) {
        int j = i - NQKV - NO;
        bqkv[j] = (j < 768) ? bq[j] : (j < 1536 ? bk[j - 768] : bv[j - 1536]);
    }
}

// ---------- 256x256 8-wave m201-style phase-pipelined bf16 GEMM, K=768 ----------
// Frag-major LDS (zero-conflict): region(buf,op,kh)=16KB, frag read = region +
// msub*1024 + lane*16. Phase = {ds_read frags; stage; BAR; lgkmcnt(0); setprio;
// 16 MFMA; setprio; [vmcnt(10)]; BAR}. Stage targets last-read >=1 barrier ago.
// MODE 0: C -> QT/KT (transposed via LDS bounce) and V row-major (+bias).
// MODE 1: C fp32 row-major (+bo), BT per-batch.
template <int MODE>
__global__ __launch_bounds__(512, 1) void gemm256(
    const bf16* __restrict__ A, const bf16* __restrict__ BT,
    bf16* __restrict__ QT, bf16* __restrict__ KT, bf16* __restrict__ V,
    const float* __restrict__ bias,
    float* __restrict__ Cout, const float* __restrict__ bo) {
    __shared__ char lds[131072];
    const int NKT = 12;
    const int tid = threadIdx.x;
    const int lane = tid & 63, wid = tid >> 6;
    const int wm = wid >> 2, wn = wid & 3;
    const int lrow = lane & 15, lk = lane >> 4;

    int nwg = gridDim.x * gridDim.y;
    int bid = blockIdx.y * gridDim.x + blockIdx.x;
    int swz = (bid & 7) * (nwg >> 3) + (bid >> 3);
    int bx = swz % gridDim.x, by = swz / gridDim.x;
    const int m0 = by * 256, n0 = bx * 256;

    const bf16* bt = BT + (MODE == 1 ? (size_t)(m0 >> 12) * 589824 : 0);

    const int srow = wid * 16 + lrow;          // staged rows srow, srow+128
    const int scol = ((lane >> 4) & 3) << 3;   // 8-elem offset in K-half

    f32x4 acc[8][4] = {};

#define STAGE(tbuf, isb, skh, sktv) do {                                           \
    int skt_ = (sktv); if (skt_ >= NKT) skt_ = NKT - 1;                            \
    const bf16* gp_ = ((isb) ? bt + (size_t)(n0 + srow) * 768                      \
                             : A  + (size_t)(m0 + srow) * 768)                     \
                      + skt_ * 64 + (skh) * 32 + scol;                             \
    char* lp_ = lds + (tbuf) * 65536 + (isb) * 32768 + (skh) * 16384 + wid * 1024; \
    gload_lds16(gp_, lp_);                                                         \
    gload_lds16(gp_ + (size_t)128 * 768, lp_ + 8192);                              \
} while (0)

#define VMC10 asm volatile("s_waitcnt vmcnt(10)" ::: "memory")
#define BAR   __builtin_amdgcn_s_barrier()

#define PH(cbuf, KH, CM, RB, STG, DOV) do {                                        \
    const char* ab_ = lds + (cbuf) * 65536 + (KH) * 16384;                         \
    _Pragma("unroll") for (int mi = 0; mi < 4; ++mi)                               \
        afr[mi] = *(const bf16x8*)(ab_ + (wm * 8 + (CM) * 4 + mi) * 1024 + lane * 16); \
    if (RB) {                                                                      \
        const char* bb_ = ab_ + 32768;                                             \
        _Pragma("unroll") for (int ni = 0; ni < 4; ++ni)                           \
            bfr[ni] = *(const bf16x8*)(bb_ + (wn * 4 + ni) * 1024 + lane * 16);    \
    }                                                                              \
    STG;                                                                           \
    BAR;                                                                           \
    asm volatile("s_waitcnt lgkmcnt(0)" ::: "memory");                             \
    __builtin_amdgcn_s_setprio(1);                                                 \
    _Pragma("unroll") for (int mi = 0; mi < 4; ++mi)                               \
    _Pragma("unroll") for (int ni = 0; ni < 4; ++ni)                               \
        acc[(CM) * 4 + mi][ni] = __builtin_amdgcn_mfma_f32_16x16x32_bf16(          \
            afr[mi], bfr[ni], acc[(CM) * 4 + mi][ni], 0, 0, 0);                    \
    __builtin_amdgcn_s_setprio(0);                                                 \
    if (DOV) VMC10;                                                                \
    BAR;                                                                           \
} while (0)

    bf16x8 afr[4], bfr[4];

    // prologue: FIFO [Bh0(0) Ah0(0) Bh1(0) Ah1(0) Bh0(1) Ah0(1) Bh1(1)] = 14 loads
    STAGE(0, 1, 0, 0);
    STAGE(0, 0, 0, 0);
    STAGE(0, 1, 1, 0);
    STAGE(0, 0, 1, 0);
    STAGE(1, 1, 0, 1);
    STAGE(1, 0, 0, 1);
    STAGE(1, 1, 1, 1);
    VMC10; BAR;   // drains Bh0(0), Ah0(0)

    for (int i = 0; i < NKT; ++i) {
        const int cb = i & 1, nb = cb ^ 1;
        PH(cb, 0, 0, 1, STAGE(nb, 0, 1, i + 1), 0);  // p1: A-h0 CM0 + B-h0 | stage A-h1(i+1)
        PH(cb, 0, 1, 0, STAGE(cb, 1, 0, i + 2), 1);  // p2: A-h0 CM1       | stage B-h0(i+2) | vmcnt
        PH(cb, 1, 0, 1, STAGE(cb, 0, 0, i + 2), 0);  // p3: A-h1 CM0 + B-h1| stage A-h0(i+2)
        PH(cb, 1, 1, 0, STAGE(cb, 1, 1, i + 2), 1);  // p4: A-h1 CM1       | stage B-h1(i+2) | vmcnt
    }

#undef STAGE
#undef PH
#undef VMC10
#undef BAR

    if (MODE == 0) {
        const int which = n0 / 768;
        if (which < 2) {
            // transposed store via LDS bounce: [col 0..127][256 toks], stride 528B
            bf16* T = (which == 0) ? QT : KT;
            const int b = m0 >> 12;
            const int tok0 = m0 & 4095;
            const int chan0 = n0 - which * 768;
            char* eb = lds;
            const int col = tid >> 2, q = tid & 3;
#pragma unroll
            for (int s = 0; s < 2; ++s) {
                if ((wn >> 1) == s) {
#pragma unroll
                    for (int ri = 0; ri < 8; ++ri)
#pragma unroll
                        for (int ni = 0; ni < 4; ++ni) {
                            int gcol = n0 + wn * 64 + ni * 16 + lrow;
                            float bia = bias[gcol];
                            int cloc = (wn & 1) * 64 + ni * 16 + lrow;
                            int row = wm * 128 + ri * 16 + lk * 4;
                            us4 pk;
                            pk[0] = f2bu(acc[ri][ni][0] + bia);
                            pk[1] = f2bu(acc[ri][ni][1] + bia);
                            pk[2] = f2bu(acc[ri][ni][2] + bia);
                            pk[3] = f2bu(acc[ri][ni][3] + bia);
                            *(us4*)(eb + cloc * 528 + row * 2) = pk;
                        }
                }
                __syncthreads();
                size_t gbase = ((size_t)b * 768 + chan0 + s * 128 + col) * 4096 + tok0;
#pragma unroll
                for (int it = 0; it < 8; ++it) {
                    int eo = q * 64 + it * 8;
                    u16x8 v = *(const u16x8*)(eb + col * 528 + eo * 2);
                    *(u16x8*)&T[gbase + eo] = v;
                }
                __syncthreads();
            }
        } else {
#pragma unroll
            for (int ri = 0; ri < 8; ++ri)
#pragma unroll
                for (int ni = 0; ni < 4; ++ni) {
                    int gcol = n0 + wn * 64 + ni * 16 + lrow;
                    int chan = gcol - 1536;
                    float bia = bias[gcol];
                    size_t r0 = (size_t)(m0 + wm * 128 + ri * 16 + lk * 4);
#pragma unroll
                    for (int r = 0; r < 4; ++r)
                        V[(r0 + r) * 768 + chan] = __float2bfloat16(acc[ri][ni][r] + bia);
                }
        }
    } else {
#pragma unroll
        for (int ri = 0; ri < 8; ++ri)
#pragma unroll
            for (int ni = 0; ni < 4; ++ni) {
                int col = n0 + wn * 64 + ni * 16 + lrow;
                float bia = bo[col];
                size_t r0 = (size_t)(m0 + wm * 128 + ri * 16 + lk * 4);
#pragma unroll
                for (int r = 0; r < 4; ++r)
                    Cout[(r0 + r) * 768 + col] = acc[ri][ni][r] + bia;
            }
    }
}

// ---------- Gram via MFMA over tokens + fused ssq/ssk ----------
__global__ __launch_bounds__(256) void gram_mfma_kernel(
    const bf16* __restrict__ QT, const bf16* __restrict__ KT,
    float* __restrict__ G, float* __restrict__ ssq, float* __restrict__ ssk) {
    const int kc = blockIdx.x, bh = blockIdx.y;
    const int b = bh / NHEAD, h = bh % NHEAD;
    const int tid = threadIdx.x, lane = tid & 63, w = tid >> 6;
    const int lrow = lane & 15, lk = lane >> 4;
    const int t0 = kc * 512 + w * 128;

    f32x4 acc[4][4] = {};
    float sqp[4] = {}, skp[4] = {};
    const size_t qbase = ((size_t)b * 768 + h * 64) * 4096;

#pragma unroll
    for (int kk = 0; kk < 4; ++kk) {
        bf16x8 a[4], bb[4];
#pragma unroll
        for (int mi = 0; mi < 4; ++mi)
            a[mi] = *(const bf16x8*)(QT + qbase + (size_t)(mi * 16 + lrow) * 4096 +
                                     t0 + kk * 32 + lk * 8);
#pragma unroll
        for (int ni = 0; ni < 4; ++ni)
            bb[ni] = *(const bf16x8*)(KT + qbase + (size_t)(ni * 16 + lrow) * 4096 +
                                      t0 + kk * 32 + lk * 8);
#pragma unroll
        for (int mi = 0; mi < 4; ++mi) {
#pragma unroll
            for (int j = 0; j < 8; ++j) {
                float qv = b2f((unsigned short)a[mi][j]);
                float kv = b2f((unsigned short)bb[mi][j]);
                sqp[mi] = fmaf(qv, qv, sqp[mi]);
                skp[mi] = fmaf(kv, kv, skp[mi]);
            }
        }
#pragma unroll
        for (int mi = 0; mi < 4; ++mi)
#pragma unroll
            for (int ni = 0; ni < 4; ++ni)
                acc[mi][ni] = __builtin_amdgcn_mfma_f32_16x16x32_bf16(a[mi], bb[ni], acc[mi][ni], 0, 0, 0);
    }

#pragma unroll
    for (int mi = 0; mi < 4; ++mi) {
        float vq = sqp[mi], vk = skp[mi];
        vq += __shfl_down(vq, 32); vq += __shfl_down(vq, 16);
        vk += __shfl_down(vk, 32); vk += __shfl_down(vk, 16);
        if (lane < 16) {
            atomicAdd(&ssq[b * 768 + h * 64 + mi * 16 + lrow], vq);
            atomicAdd(&ssk[b * 768 + h * 64 + mi * 16 + lrow], vk);
        }
    }

    float* g = G + (size_t)bh * 4096;
#pragma unroll
    for (int mi = 0; mi < 4; ++mi)
#pragma unroll
        for (int ni = 0; ni < 4; ++ni)
#pragma unroll
            for (int r = 0; r < 4; ++r) {
                int e = mi * 16 + lk * 4 + r;
                int j = ni * 16 + lrow;
                atomicAdd(&g[e * 64 + j], acc[mi][ni][r]);
            }
}

// ---------- normalize + softmax + /sqrt(E); store attnA[e][q] bf16 ----------
__global__ __launch_bounds__(64) void softmax_kernel(
    const float* __restrict__ G, const float* __restrict__ ssq, const float* __restrict__ ssk,
    bf16* __restrict__ attnA) {
    int bh = blockIdx.x; int b = bh / NHEAD, h = bh % NHEAD;
    int e = threadIdx.x;
    const float* g = G + (size_t)bh * 4096 + e * 64;
    float nq = fmaxf(sqrtf(ssq[b * 768 + h * 64 + e]), 1e-12f);
    float row[64];
    float mx = -1e30f;
#pragma unroll
    for (int j = 0; j < 64; ++j) {
        float nk = fmaxf(sqrtf(ssk[b * 768 + h * 64 + j]), 1e-12f);
        float en = g[j] / (nq * nk);
        row[j] = en;
        mx = fmaxf(mx, en);
    }
    float s = 0.f;
#pragma unroll
    for (int j = 0; j < 64; ++j) { row[j] = __expf(row[j] - mx); s += row[j]; }
    float inv = 0.036084391824351615f / s;
#pragma unroll
    for (int j = 0; j < 64; ++j)
        attnA[(size_t)bh * 4096 + e * 64 + j] = __float2bfloat16(row[j] * inv);
}

// ---------- Wtilde: WtT[b][n][h*64+e] = sum_q attn[b,e,h,q] Wo[h*64+q][n] ----------
__global__ __launch_bounds__(256) void wtilde_kernel(
    const bf16* __restrict__ WoT, const bf16* __restrict__ attnA,
    bf16* __restrict__ WtT) {
    const int ns = blockIdx.x, bh = blockIdx.y;
    const int b = bh / NHEAD, h = bh % NHEAD;
    const int tid = threadIdx.x, lane = tid & 63, w = tid >> 6;
    const int lrow = lane & 15, lk = lane >> 4;
    const int nbase = ns * 192 + w * 48;

    f32x4 acc[3][4] = {};
#pragma unroll
    for (int kk = 0; kk < 2; ++kk) {
        bf16x8 a[3], bb[4];
#pragma unroll
        for (int mi = 0; mi < 3; ++mi)
            a[mi] = *(const bf16x8*)(WoT + (size_t)(nbase + mi * 16 + lrow) * 768 +
                                     h * 64 + kk * 32 + lk * 8);
#pragma unroll
        for (int ni = 0; ni < 4; ++ni)
            bb[ni] = *(const bf16x8*)(attnA + (size_t)bh * 4096 +
                                      (ni * 16 + lrow) * 64 + kk * 32 + lk * 8);
#pragma unroll
        for (int mi = 0; mi < 3; ++mi)
#pragma unroll
            for (int ni = 0; ni < 4; ++ni)
                acc[mi][ni] = __builtin_amdgcn_mfma_f32_16x16x32_bf16(a[mi], bb[ni], acc[mi][ni], 0, 0, 0);
    }
#pragma unroll
    for (int mi = 0; mi < 3; ++mi)
#pragma unroll
        for (int ni = 0; ni < 4; ++ni)
#pragma unroll
            for (int r = 0; r < 4; ++r) {
                int n = nbase + mi * 16 + lk * 4 + r;
                int e = ni * 16 + lrow;
                WtT[((size_t)b * 768 + n) * 768 + h * 64 + e] = __float2bfloat16(acc[mi][ni][r]);
            }
}

// ---------- launch ----------
extern "C" void kernel_launch(void* const* d_in, const int* in_sizes, int n_in,
                              void* d_out, int out_size, void* d_ws, size_t ws_size,
                              hipStream_t stream) {
    const float* x  = (const float*)d_in[0];
    const float* Wq = (const float*)d_in[1];
    const float* bq = (const float*)d_in[2];
    const float* Wk = (const float*)d_in[3];
    const float* bk = (const float*)d_in[4];
    const float* Wv = (const float*)d_in[5];
    const float* bv = (const float*)d_in[6];
    const float* Wo = (const float*)d_in[7];
    const float* bo = (const float*)d_in[8];
    float* out = (float*)d_out;

    char* ws = (char*)d_ws;
    bf16*  xb    = (bf16*)(ws + 0);               // 50331648 ; later reused for WtT
    bf16*  WqkvT = (bf16*)(ws + 50331648);        // 3538944
    bf16*  WoT   = (bf16*)(ws + 53870592);        // 1179648
    float* bqkv  = (float*)(ws + 55050240);       // 9216
    bf16*  QT    = (bf16*)(ws + 55059456);        // 50331648  [b][768][4096]
    bf16*  KT    = (bf16*)(ws + 105391104);       // 50331648  [b][768][4096]
    bf16*  Vb    = (bf16*)(ws + 155722752);       // 50331648  [bn][768]
    float* ssq   = (float*)(ws + 206054400);      // 24576
    float* ssk   = (float*)(ws + 206078976);      // 24576
    float* G     = (float*)(ws + 206103552);      // 1572864
    bf16*  attnA = (bf16*)(ws + 207676416);       // 786432
    bf16*  WtT   = xb;                            // alias: xb dead after QKV GEMM

    hipMemsetAsync(ws + 206054400, 0, 24576 + 24576 + 1572864, stream);

    cast_x_kernel<<<12288, 256, 0, stream>>>(x, xb, BNTOK * EMB / 8);
    prep_w_kernel<<<9225, 256, 0, stream>>>(Wq, Wk, Wv, Wo, bq, bk, bv, WqkvT, WoT, bqkv);

    gemm256<0><<<dim3(9, 128), 512, 0, stream>>>(xb, WqkvT, QT, KT, Vb, bqkv, nullptr, nullptr);

    gram_mfma_kernel<<<dim3(8, 96), 256, 0, stream>>>(QT, KT, G, ssq, ssk);
    softmax_kernel<<<96, 64, 0, stream>>>(G, ssq, ssk, attnA);
    wtilde_kernel<<<dim3(4, 96), 256, 0, stream>>>(WoT, attnA, WtT);

    gemm256<1><<<dim3(3, 128), 512, 0, stream>>>(Vb, WtT, nullptr, nullptr, nullptr, nullptr, out, bo);
}